// Round 18
// baseline (106.715 us; speedup 1.0000x reference)
//
#include <hip/hip_runtime.h>
#include <hip/hip_bf16.h>
#include <cstdint>
#include <math.h>

#define LSEQ 2048
#define BATCH 2
#define NHEAD 16
#define DHEAD 64
#define DMODEL 1024
#define ROWS (BATCH*LSEQ)

typedef __bf16 bf16x8 __attribute__((ext_vector_type(8)));
typedef float f32x4 __attribute__((ext_vector_type(4)));
typedef unsigned short u16;

#define GLD(lds_base, src_g) \
  __builtin_amdgcn_global_load_lds((const __attribute__((address_space(1))) void*)(src_g), \
                                   (__attribute__((address_space(3))) void*)(lds_base), 16, 0, 0)
#define VM(n) asm volatile("s_waitcnt vmcnt(" #n ")" ::: "memory")

__device__ __forceinline__ u16 f2bf(float f) {
  unsigned int u = __float_as_uint(f);
  u += 0x7fffu + ((u >> 16) & 1u);
  return (u16)(u >> 16);
}
__device__ __forceinline__ float bf2f(u16 u) {
  return __uint_as_float(((unsigned)u) << 16);
}

// ---- fused prep: ln1 (4096) | wqkv^T (3072) | wout^T (1024) | rope+bnd (256) --
__global__ __launch_bounds__(256) void k_prep(const float* __restrict__ x, const float* __restrict__ ln1w,
                                              const float* __restrict__ ln1b, u16* __restrict__ hbuf,
                                              const float* __restrict__ wqkv, u16* __restrict__ wqkvT,
                                              const float* __restrict__ wout, u16* __restrict__ woutT,
                                              const int* __restrict__ seq, int* __restrict__ bnd,
                                              float* __restrict__ cosb, float* __restrict__ sinb) {
  __shared__ float tile[32][33];
  __shared__ float rb[2][4];
  const int bid = blockIdx.x, t = threadIdx.x;
  if (bid < 4096) {
    const int row = bid;
    const float4 xv = ((const float4*)(x + (size_t)row * DMODEL))[t];
    float s = xv.x + xv.y + xv.z + xv.w;
    float s2 = xv.x * xv.x + xv.y * xv.y + xv.z * xv.z + xv.w * xv.w;
#pragma unroll
    for (int m2 = 1; m2 < 64; m2 <<= 1) { s += __shfl_xor(s, m2); s2 += __shfl_xor(s2, m2); }
    int wv = t >> 6;
    if ((t & 63) == 0) { rb[0][wv] = s; rb[1][wv] = s2; }
    __syncthreads();
    s  = rb[0][0] + rb[0][1] + rb[0][2] + rb[0][3];
    s2 = rb[1][0] + rb[1][1] + rb[1][2] + rb[1][3];
    float mu = s * (1.0f / DMODEL);
    float rs = rsqrtf(s2 * (1.0f / DMODEL) - mu * mu + 1e-5f);
    const float4 wv4 = ((const float4*)ln1w)[t];
    const float4 bv4 = ((const float4*)ln1b)[t];
    ushort4 o;
    o.x = f2bf((xv.x - mu) * rs * wv4.x + bv4.x);
    o.y = f2bf((xv.y - mu) * rs * wv4.y + bv4.y);
    o.z = f2bf((xv.z - mu) * rs * wv4.z + bv4.z);
    o.w = f2bf((xv.w - mu) * rs * wv4.w + bv4.w);
    ((ushort4*)(hbuf + (size_t)row * DMODEL))[t] = o;
  } else if (bid < 4096 + 3072 + 1024) {
    const float* in; u16* out; int R, C, bx, by;
    if (bid < 4096 + 3072) { int rel = bid - 4096; in = wqkv; out = wqkvT; R = 1024; C = 3072; bx = rel % 96; by = rel / 96; }
    else                   { int rel = bid - 7168; in = wout; out = woutT; R = 1024; C = 1024; bx = rel % 32; by = rel / 32; }
    int c0 = bx * 32, r0 = by * 32;
    int tx = t & 31, ty = t >> 5;
#pragma unroll
    for (int i = 0; i < 32; i += 8)
      tile[ty + i][tx] = in[(size_t)(r0 + ty + i) * C + (c0 + tx)];
    __syncthreads();
#pragma unroll
    for (int i = 0; i < 32; i += 8)
      out[(size_t)(c0 + ty + i) * R + (r0 + tx)] = f2bf(tile[tx][ty + i]);
  } else {
    const int rel = bid - 8192;
    if (rel == 0 && t < BATCH * 5) {
      int b = t / 5, s = t % 5;
      const int* row = seq + b * LSEQ;
      int lo = 0, hi = LSEQ;
      while (lo < hi) { int mid = (lo + hi) >> 1; if (row[mid] < s) lo = mid + 1; else hi = mid; }
      bnd[b * 5 + s] = lo;
    }
    int idx = rel * 256 + t;
    if (idx < LSEQ * 32) {
      int l = idx >> 5, f = idx & 31;
      double inv = pow(10000.0, -(double)f / 32.0);
      float ang = (float)l * (float)inv;
      cosb[idx] = cosf(ang);
      sinb[idx] = sinf(ang);
    }
  }
}

// ============ 128x192 4-phase GEMM, C = A @ B^T (80 KB LDS -> 2 blocks/CU) =====
template<int OUTMODE>
__global__ __launch_bounds__(512, 4) void k_gemm256(const u16* __restrict__ A, const u16* __restrict__ B,
                                                    void* __restrict__ Cv, int M, int N, int K) {
  __shared__ __align__(16) u16 As[2][128 * 64];
  __shared__ __align__(16) u16 Bs[2][192 * 64];
  const int t = threadIdx.x, lane = t & 63, w = t >> 6;
  const int wr = w >> 2, wc = w & 3;
  const int nbx = N / 192;
  const int nwg = nbx * (M >> 7);
  const int cpx = nwg >> 3;
  const int bid = blockIdx.x;
  const int sw = (bid & 7) * cpx + (bid >> 3);
  const int m0 = (sw / nbx) * 128, n0 = (sw % nbx) * 192;
  const int NT = K >> 6;
  const int cg16 = (lane >> 4) * 16;

  f32x4 acc[4][3] = {};
  bf16x8 af_[2][2], bf_[3][2];
  const u16* Ap = A + (size_t)m0 * K;
  const u16* Bp = B + (size_t)n0 * K;
  const int rr0 = t >> 3;
  const int sz = ((t & 7) * 8) ^ ((rr0 & 7) << 3);
  const u16* pA[2] = { Ap + (size_t)rr0 * K + sz,
                       Ap + (size_t)(rr0 + 64) * K + sz };
  const u16* pB[3] = { Bp + (size_t)rr0 * K + sz,
                       Bp + (size_t)(rr0 + 64) * K + sz,
                       Bp + (size_t)(rr0 + 128) * K + sz };

#define SA1(b, h, EO) GLD((char*)As + (b)*16384 + (h)*8192 + w*1024, pA[h] + (EO))
#define SB3(b, EO) do { \
    GLD((char*)Bs + (b)*24576 +         w*1024, pB[0] + (EO)); \
    GLD((char*)Bs + (b)*24576 +  8192 + w*1024, pB[1] + (EO)); \
    GLD((char*)Bs + (b)*24576 + 16384 + w*1024, pB[2] + (EO)); \
  } while (0)

#define READ_AF(asb, mh) do { \
    _Pragma("unroll") for (int i2 = 0; i2 < 2; i2++) { \
      const int rowA = (((mh)*2 + i2)*2 + wr)*16 + (lane & 15); \
      const int sA = (rowA & 7) << 4; \
      _Pragma("unroll") for (int kk = 0; kk < 2; kk++) \
        af_[i2][kk] = *(const bf16x8*)((const char*)(asb) + (rowA & 63)*128 + ((kk*64 + cg16) ^ sA)); \
    } } while (0)
#define READ_BF(bsb) do { \
    _Pragma("unroll") for (int j2 = 0; j2 < 3; j2++) { \
      const int rowB = (j2*4 + wc)*16 + (lane & 15); \
      const int sB = (rowB & 7) << 4; \
      _Pragma("unroll") for (int kk = 0; kk < 2; kk++) \
        bf_[j2][kk] = *(const bf16x8*)((const char*)(bsb) + rowB*128 + ((kk*64 + cg16) ^ sB)); \
    } } while (0)
#define MFMA12(mh) do { \
    _Pragma("unroll") for (int kk = 0; kk < 2; kk++) \
      _Pragma("unroll") for (int i2 = 0; i2 < 2; i2++) \
        _Pragma("unroll") for (int j2 = 0; j2 < 3; j2++) \
          acc[(mh)*2+i2][j2] = __builtin_amdgcn_mfma_f32_16x16x32_bf16( \
              af_[i2][kk], bf_[j2][kk], acc[(mh)*2+i2][j2], 0, 0, 0); \
  } while (0)

  SA1(0, 0, 0); SA1(0, 1, 0); SB3(0, 0);
  SA1(1, 0, 64);
  VM(1);
  __builtin_amdgcn_s_barrier();

  const char* a0  = (const char*)As;
  const char* a0h = a0 + 8192;
  const char* a1  = a0 + 16384;
  const char* a1h = a0 + 24576;
  const char* b0  = (const char*)Bs;
  const char* b1  = b0 + 24576;
  const int NIT = NT >> 1;
  for (int i = 0; i < NIT; i++) {
    const bool lst = (i == NIT - 1);
    READ_AF(a0, 0); READ_BF(b0);
    SA1(1, 1, 64); SB3(1, 64);
    __builtin_amdgcn_s_barrier();
    asm volatile("s_waitcnt lgkmcnt(0)" ::: "memory");
    __builtin_amdgcn_s_setprio(1); MFMA12(0); __builtin_amdgcn_s_setprio(0);
    __builtin_amdgcn_s_barrier();
    READ_AF(a0h, 1);
    if (!lst) SA1(0, 0, 128);
    __builtin_amdgcn_s_barrier();
    asm volatile("s_waitcnt lgkmcnt(0)" ::: "memory");
    __builtin_amdgcn_s_setprio(1); MFMA12(1); __builtin_amdgcn_s_setprio(0);
    if (lst) VM(0); else VM(1);
    __builtin_amdgcn_s_barrier();
    READ_AF(a1, 0); READ_BF(b1);
    if (!lst) { SA1(0, 1, 128); SB3(0, 128); }
    __builtin_amdgcn_s_barrier();
    asm volatile("s_waitcnt lgkmcnt(0)" ::: "memory");
    __builtin_amdgcn_s_setprio(1); MFMA12(0); __builtin_amdgcn_s_setprio(0);
    __builtin_amdgcn_s_barrier();
    READ_AF(a1h, 1);
    if (!lst) SA1(1, 0, 192);
    __builtin_amdgcn_s_barrier();
    asm volatile("s_waitcnt lgkmcnt(0)" ::: "memory");
    __builtin_amdgcn_s_setprio(1); MFMA12(1); __builtin_amdgcn_s_setprio(0);
    if (!lst) VM(1);
    __builtin_amdgcn_s_barrier();
    pA[0] += 128; pA[1] += 128;
    pB[0] += 128; pB[1] += 128; pB[2] += 128;
  }
#undef MFMA12
#undef READ_BF
#undef READ_AF
#undef SA1
#undef SB3

  const int cr = (lane >> 4) * 4, cc = lane & 15;
#pragma unroll
  for (int fi = 0; fi < 4; fi++)
#pragma unroll
    for (int fj = 0; fj < 3; fj++) {
      const size_t roff = (size_t)(m0 + (fi * 2 + wr) * 16 + cr) * N + (n0 + (fj * 4 + wc) * 16 + cc);
      if (OUTMODE == 0) {
        float* Cp = (float*)Cv + roff;
#pragma unroll
        for (int r = 0; r < 4; r++) Cp[(size_t)r * N] = acc[fi][fj][r];
      } else {
        u16* Cp = (u16*)Cv + roff;
#pragma unroll
        for (int r = 0; r < 4; r++) Cp[(size_t)r * N] = f2bf(acc[fi][fj][r]);
      }
    }
}

// ---- bf16 GEMM 128x64 tile, chunked XCD swizzle, single-barrier loop (GEMM2) --
template<int OUTMODE>
__global__ __launch_bounds__(256) void k_gemm_bt(const u16* __restrict__ A, const u16* __restrict__ B,
                                                 void* __restrict__ Cv, int M, int N, int K) {
  __shared__ __align__(16) u16 As[2][128 * 64];
  __shared__ __align__(16) u16 Bs[2][64 * 64];
  const int t = threadIdx.x;
  const int lane = t & 63, w = t >> 6;
  const int nbx = N >> 6;
  const int nwg = nbx * (M >> 7);
  const int cpx = nwg >> 3;
  const int bid = blockIdx.x;
  const int sw = (bid & 7) * cpx + (bid >> 3);
  const int m0 = (sw / nbx) * 128, n0 = (sw % nbx) * 64;
  const int wm = (w >> 1) * 64, wn = (w & 1) * 32;
  const int NT = K >> 6;
  f32x4 acc[4][2] = {};
  const u16* Ap = A + (size_t)m0 * K;
  const u16* Bp = B + (size_t)n0 * K;
  const int cr0 = lane >> 3, cs = lane & 7;

#define GSTAGE(bb, kt_) do { \
    _Pragma("unroll") \
    for (int s2 = 0; s2 < 4; s2++) { \
      int ch = w * 4 + s2; \
      int row = ch * 8 + cr0; \
      int cb = cs ^ (row & 7); \
      GLD((char*)As[bb] + ch * 1024, Ap + (size_t)row * K + (kt_) * 64 + cb * 8); \
    } \
    _Pragma("unroll") \
    for (int s2 = 0; s2 < 2; s2++) { \
      int ch = w * 2 + s2; \
      int row = ch * 8 + cr0; \
      int cb = cs ^ (row & 7); \
      GLD((char*)Bs[bb] + ch * 1024, Bp + (size_t)row * K + (kt_) * 64 + cb * 8); \
    } } while (0)

  GSTAGE(0, 0);
  int cur = 0;
  for (int kt = 0; kt < NT; kt++) {
    VM(0);
    __builtin_amdgcn_s_barrier();
    __builtin_amdgcn_sched_barrier(0);
    if (kt + 1 < NT) GSTAGE(cur ^ 1, kt + 1);
    const u16* asb = As[cur];
    const u16* bsb = Bs[cur];
#pragma unroll
    for (int kk = 0; kk < 2; kk++) {
      bf16x8 af[4], bfr[2];
#pragma unroll
      for (int i = 0; i < 4; i++) {
        int rowa = wm + i * 16 + (lane & 15);
        af[i] = *(const bf16x8*)((const char*)asb + rowa * 128 + ((kk * 64 + (lane >> 4) * 16) ^ ((rowa & 7) << 4)));
      }
#pragma unroll
      for (int j = 0; j < 2; j++) {
        int rowb = wn + j * 16 + (lane & 15);
        bfr[j] = *(const bf16x8*)((const char*)bsb + rowb * 128 + ((kk * 64 + (lane >> 4) * 16) ^ ((rowb & 7) << 4)));
      }
      __builtin_amdgcn_s_setprio(1);
#pragma unroll
      for (int mf = 0; mf < 4; mf++)
#pragma unroll
        for (int nf = 0; nf < 2; nf++)
          acc[mf][nf] = __builtin_amdgcn_mfma_f32_16x16x32_bf16(af[mf], bfr[nf], acc[mf][nf], 0, 0, 0);
      __builtin_amdgcn_s_setprio(0);
    }
    __builtin_amdgcn_sched_barrier(0);
    cur ^= 1;
  }
#undef GSTAGE
  const int cr = (lane >> 4) * 4, cc = lane & 15;
#pragma unroll
  for (int mf = 0; mf < 4; mf++)
#pragma unroll
    for (int nf = 0; nf < 2; nf++) {
      if (OUTMODE == 0) {
        float* Cp = (float*)Cv + (size_t)(m0 + wm + mf * 16 + cr) * N + (n0 + wn + nf * 16 + cc);
#pragma unroll
        for (int r = 0; r < 4; r++) Cp[(size_t)r * N] = acc[mf][nf][r];
      } else {
        u16* Cp = (u16*)Cv + (size_t)(m0 + wm + mf * 16 + cr) * N + (n0 + wn + nf * 16 + cc);
#pragma unroll
        for (int r = 0; r < 4; r++) Cp[(size_t)r * N] = f2bf(acc[mf][nf][r]);
      }
    }
}

// ---- fused: q/k LN+RoPE+split (4096 blocks, shfl-based) | V^T (4096 blocks) ---
__global__ __launch_bounds__(256) void k_qkv_post(const u16* __restrict__ qkv,
                                                  const float* __restrict__ qw, const float* __restrict__ kw,
                                                  const float* __restrict__ cosb, const float* __restrict__ sinb,
                                                  u16* __restrict__ Q, u16* __restrict__ K, u16* __restrict__ VT) {
  const int bid = blockIdx.x, t = threadIdx.x;
  if (bid < 4096) {
    __shared__ float rb[4][4];
    int row = bid;
    int b = row >> 11, l = row & 2047;
    const u16* base = qkv + (size_t)row * 3072;
    ushort4 qu = ((const ushort4*)base)[t];
    ushort4 ku = ((const ushort4*)(base + 1024))[t];
    float qx = bf2f(qu.x), qy = bf2f(qu.y), qz = bf2f(qu.z), qw_ = bf2f(qu.w);
    float kx = bf2f(ku.x), ky = bf2f(ku.y), kz = bf2f(ku.z), kw_ = bf2f(ku.w);
    float red[4];
    red[0] = qx + qy + qz + qw_;
    red[1] = qx * qx + qy * qy + qz * qz + qw_ * qw_;
    red[2] = kx + ky + kz + kw_;
    red[3] = kx * kx + ky * ky + kz * kz + kw_ * kw_;
#pragma unroll
    for (int i = 0; i < 4; i++)
#pragma unroll
      for (int m2 = 1; m2 < 64; m2 <<= 1) red[i] += __shfl_xor(red[i], m2);
    int w = t >> 6;
    if ((t & 63) == 0) { rb[w][0] = red[0]; rb[w][1] = red[1]; rb[w][2] = red[2]; rb[w][3] = red[3]; }
    __syncthreads();
    float S1 = rb[0][0] + rb[1][0] + rb[2][0] + rb[3][0];
    float S2 = rb[0][1] + rb[1][1] + rb[2][1] + rb[3][1];
    float S3 = rb[0][2] + rb[1][2] + rb[2][2] + rb[3][2];
    float S4 = rb[0][3] + rb[1][3] + rb[2][3] + rb[3][3];
    float muq = S1 * (1.0f / DMODEL), rsq = rsqrtf(S2 * (1.0f / DMODEL) - muq * muq + 1e-5f);
    float muk = S3 * (1.0f / DMODEL), rsk = rsqrtf(S4 * (1.0f / DMODEL) - muk * muk + 1e-5f);
    float4 qwv = ((const float4*)qw)[t];
    float4 kwv = ((const float4*)kw)[t];
    float qn[4], kn[4];
    qn[0] = (qx - muq) * rsq * qwv.x;  kn[0] = (kx - muk) * rsk * kwv.x;
    qn[1] = (qy - muq) * rsq * qwv.y;  kn[1] = (ky - muk) * rsk * kwv.y;
    qn[2] = (qz - muq) * rsq * qwv.z;  kn[2] = (kz - muk) * rsk * kwv.z;
    qn[3] = (qw_ - muq) * rsq * qwv.w; kn[3] = (kw_ - muk) * rsk * kwv.w;
    const float sgn = (t & 8) ? 1.0f : -1.0f;
    int d0 = t * 4;
    int hh = d0 >> 6;
    union { ushort4 v4; u16 e[4]; } qo, ko;
#pragma unroll
    for (int i = 0; i < 4; i++) {
      int fr = (t & 7) * 4 + i;
      float c = cosb[l * 32 + fr], s = sinb[l * 32 + fr];
      float q2 = sgn * __shfl_xor(qn[i], 8);
      float k2 = sgn * __shfl_xor(kn[i], 8);
      qo.e[i] = f2bf(qn[i] * c + q2 * s);
      ko.e[i] = f2bf(kn[i] * c + k2 * s);
    }
    size_t oidx = ((size_t)(b * NHEAD + hh) * LSEQ + l) * DHEAD + (d0 & 63);
    *(ushort4*)(Q + oidx) = qo.v4;
    *(ushort4*)(K + oidx) = ko.v4;
  } else {
    __shared__ u16 vtile[32][33];
    const int rel = bid - 4096;
    const int hd = rel >> 7;
    const int tl = rel & 127;
    const int d0 = (tl & 1) * 32, l0 = (tl >> 1) * 32;
    const int gl = (hd >> 4) * LSEQ;
    const u16* ip = qkv + (size_t)(gl + l0) * 3072 + 2048 + (hd & 15) * 64 + d0;
    u16* op = VT + (size_t)hd * LSEQ * DHEAD + (size_t)d0 * LSEQ + l0;
    int tx = t & 31, ty = t >> 5;
#pragma unroll
    for (int i = 0; i < 32; i += 8)
      vtile[ty + i][tx] = ip[(size_t)(ty + i) * 3072 + tx];
    __syncthreads();
#pragma unroll
    for (int i = 0; i < 32; i += 8)
      op[(size_t)(ty + i) * LSEQ + tx] = vtile[tx][ty + i];
  }
}

// -- flash attention: QBLK=64, 4 waves x 16 q-rows, 40 KB LDS -> 4 blocks/CU ----
__global__ __launch_bounds__(256) void k_attn(const u16* __restrict__ Q, const u16* __restrict__ Kb,
                                              const u16* __restrict__ VTb, const int* __restrict__ seq,
                                              const int* __restrict__ bnd, u16* __restrict__ ctx) {
  __shared__ __align__(16) u16 Ks[2][64 * 64];   // 8 KB / buf
  __shared__ __align__(16) u16 Vs[2][64 * 64];   // 8 KB / buf
  __shared__ __align__(16) u16 Pw[4][16 * 64];   // 2 KB / wave (40 KB total)

  const int bid = blockIdx.x;
  const int sw = (bid & 7) * 128 + (bid >> 3);   // XCD-chunked (nwg = 1024)
  const int qt = sw & 31, h = (sw >> 5) & 15, b = sw >> 9;
  const int t = threadIdx.x, l = t & 63, w = t >> 6;   // 4 waves
  const int c = l & 15, g = l >> 4;
  const int q0 = qt * 64;
  const size_t hoff = (size_t)(b * NHEAD + h) * LSEQ * DHEAD;
  const u16* Qg = Q + hoff;
  const u16* Kg = Kb + hoff;
  const u16* Vg = VTb + hoff;   // [d][l]
  const int* seqb = seq + b * LSEQ;
  const int* bnd5 = bnd + b * 5;

  const int qw0 = q0 + w * 16;
  const int myq = qw0 + c;
  const int sq = seqb[myq];
  const int lo = bnd5[sq], hi = bnd5[sq + 1];
  const int wlo = bnd5[seqb[qw0]];
  const int whi = bnd5[seqb[qw0 + 15] + 1];
  int kbeg = bnd5[seqb[q0]] & ~63;
  int kend = (bnd5[seqb[q0 + 63] + 1] + 63) & ~63;
  if (kend > LSEQ) kend = LSEQ;

  bf16x8 qf[2];
  qf[0] = *(const bf16x8*)(Qg + (size_t)myq * 64 + g * 8);
  qf[1] = *(const bf16x8*)(Qg + (size_t)myq * 64 + 32 + g * 8);

  f32x4 acc[4] = {};
  float lsum = 0.f;

  // staging: 256 thr x 16B covers rows 0..31; second GLD covers rows 32..63.
  // (rr+32)&7 == rr&7 so the stored swizzle key matches the read key.
  const int rr = t >> 3;                          // 0..31
  const int szk = ((t & 7) * 8) ^ ((rr & 7) << 3);
  const u16* pK  = Kg + (size_t)rr * 64 + szk;
  const u16* pK2 = pK + (size_t)32 * 64;
  const u16* pV  = Vg + (size_t)rr * LSEQ + szk;
  const u16* pV2 = pV + (size_t)32 * LSEQ;

#define STAGE(bb, kt_) do { \
    GLD((char*)Ks[bb] +        w * 1024, pK  + (size_t)(kt_) * 64); \
    GLD((char*)Ks[bb] + 4096 + w * 1024, pK2 + (size_t)(kt_) * 64); \
    GLD((char*)Vs[bb] +        w * 1024, pV  + (kt_)); \
    GLD((char*)Vs[bb] + 4096 + w * 1024, pV2 + (kt_)); \
  } while (0)

  STAGE(0, kbeg);
  int cur = 0;
  for (int kt = kbeg; kt < kend; kt += 64) {
    VM(0);
    __builtin_amdgcn_s_barrier();
    __builtin_amdgcn_sched_barrier(0);
    if (kt + 64 < kend) STAGE(cur ^ 1, kt + 64);
    if (kt < whi && kt + 64 > wlo) {
      const u16* ksb = Ks[cur];
      const u16* vsb = Vs[cur];
      f32x4 st[4] = {};
#pragma unroll
      for (int kk = 0; kk < 2; kk++) {
        bf16x8 kf[4];
#pragma unroll
        for (int i = 0; i < 4; i++) {
          int row = i * 16 + c;
          kf[i] = *(const bf16x8*)((const char*)ksb + row * 128 + ((kk * 64 + g * 16) ^ ((row & 7) << 4)));
        }
        __builtin_amdgcn_s_setprio(1);
#pragma unroll
        for (int i = 0; i < 4; i++)
          st[i] = __builtin_amdgcn_mfma_f32_16x16x32_bf16(kf[i], qf[kk], st[i], 0, 0, 0);
        __builtin_amdgcn_s_setprio(0);
      }
      const int kb0 = kt + g * 4;
#pragma unroll
      for (int i = 0; i < 4; i++) {
        float p[4];
#pragma unroll
        for (int r = 0; r < 4; r++) {
          int kglob = kb0 + i * 16 + r;
          bool ok = ((unsigned)(kglob - lo)) < ((unsigned)(hi - lo));
          float x = ok ? fmaf(st[i][r], 0.125f, -8.0f) : -1e30f;
          p[r] = __expf(x);
          lsum += p[r];
        }
        unsigned w0, w1;
        asm("v_cvt_pk_bf16_f32 %0, %1, %2" : "=v"(w0) : "v"(p[0]), "v"(p[1]));
        asm("v_cvt_pk_bf16_f32 %0, %1, %2" : "=v"(w1) : "v"(p[2]), "v"(p[3]));
        uint2 wp; wp.x = w0; wp.y = w1;
        *(uint2*)((char*)Pw[w] + c * 128 + ((i * 32 + g * 8) ^ ((c & 7) << 4))) = wp;
      }
#pragma unroll
      for (int kk = 0; kk < 2; kk++) {
        bf16x8 pa = *(const bf16x8*)((char*)Pw[w] + c * 128 + ((kk * 64 + g * 16) ^ ((c & 7) << 4)));
        bf16x8 vf[4];
#pragma unroll
        for (int df = 0; df < 4; df++) {
          int row = df * 16 + c;
          vf[df] = *(const bf16x8*)((const char*)vsb + row * 128 + ((kk * 64 + g * 16) ^ ((row & 7) << 4)));
        }
        __builtin_amdgcn_s_setprio(1);
#pragma unroll
        for (int df = 0; df < 4; df++)
          acc[df] = __builtin_amdgcn_mfma_f32_16x16x32_bf16(pa, vf[df], acc[df], 0, 0, 0);
        __builtin_amdgcn_s_setprio(0);
      }
    }
    __builtin_amdgcn_sched_barrier(0);
    cur ^= 1;
  }
#undef STAGE

  lsum += __shfl_xor(lsum, 16);
  lsum += __shfl_xor(lsum, 32);
#pragma unroll
  for (int r = 0; r < 4; r++) {
    float lr = __shfl(lsum, g * 4 + r, 64);
    float rls = 1.0f / lr;
    int qrow = qw0 + g * 4 + r;
    u16* op = ctx + (size_t)(b * LSEQ + qrow) * DMODEL + h * 64 + c;
#pragma unroll
    for (int df = 0; df < 4; df++)
      op[df * 16] = f2bf(acc[df][r] * rls);
  }
}

// ---------------- launch --------------------------------------------------------
extern "C" void kernel_launch(void* const* d_in, const int* in_sizes, int n_in,
                              void* d_out, int out_size, void* d_ws, size_t ws_size,
                              hipStream_t stream) {
  const float* x    = (const float*)d_in[0];
  const int*   seq  = (const int*)d_in[1];
  const float* ln1w = (const float*)d_in[2];
  const float* ln1b = (const float*)d_in[3];
  const float* wqkv = (const float*)d_in[4];
  const float* qlnw = (const float*)d_in[5];
  const float* klnw = (const float*)d_in[6];
  const float* wout = (const float*)d_in[7];
  float* out = (float*)d_out;

  char* p = (char*)d_ws;
  u16* wqkvT = (u16*)p;  p += (size_t)3072 * 1024 * 2;
  u16* woutT = (u16*)p;  p += (size_t)1024 * 1024 * 2;
  u16* hbuf  = (u16*)p;  p += (size_t)ROWS * DMODEL * 2;
  u16* Qb    = (u16*)p;  p += (size_t)ROWS * DMODEL * 2;
  u16* Kbuf  = (u16*)p;  p += (size_t)ROWS * DMODEL * 2;
  u16* VTbuf = (u16*)p;  p += (size_t)ROWS * DMODEL * 2;
  u16* ctxb  = (u16*)p;  p += (size_t)ROWS * DMODEL * 2;
  float* cosb = (float*)p; p += (size_t)LSEQ * 32 * 4;
  float* sinb = (float*)p; p += (size_t)LSEQ * 32 * 4;
  int* bnd   = (int*)p;  p += 256;
  u16* qkv   = (u16*)p;  p += (size_t)ROWS * 3072 * 2;

  k_prep<<<8448, 256, 0, stream>>>(x, ln1w, ln1b, hbuf, wqkv, wqkvT, wout, woutT, seq, bnd, cosb, sinb);
  k_gemm256<1><<<(ROWS / 128) * (3072 / 192), 512, 0, stream>>>(hbuf, wqkvT, (void*)qkv, ROWS, 3072, 1024);
  k_qkv_post<<<8192, 256, 0, stream>>>(qkv, qlnw, klnw, cosb, sinb, Qb, Kbuf, VTbuf);
  k_attn<<<BATCH * NHEAD * (LSEQ / 64), 256, 0, stream>>>(Qb, Kbuf, VTbuf, seq, bnd, ctxb);
  k_gemm_bt<0><<<(ROWS / 128) * (1024 / 64), 256, 0, stream>>>(ctxb, woutT, (void*)out, ROWS, 1024, 1024);
}

// Round 19
// 102.004 us; speedup vs baseline: 1.0462x; 1.0462x over previous
//
#include <hip/hip_runtime.h>
#include <hip/hip_bf16.h>
#include <cstdint>
#include <math.h>

#define LSEQ 2048
#define BATCH 2
#define NHEAD 16
#define DHEAD 64
#define DMODEL 1024
#define ROWS (BATCH*LSEQ)

typedef __bf16 bf16x8 __attribute__((ext_vector_type(8)));
typedef float f32x4 __attribute__((ext_vector_type(4)));
typedef unsigned short u16;

#define GLD(lds_base, src_g) \
  __builtin_amdgcn_global_load_lds((const __attribute__((address_space(1))) void*)(src_g), \
                                   (__attribute__((address_space(3))) void*)(lds_base), 16, 0, 0)
#define VM(n) asm volatile("s_waitcnt vmcnt(" #n ")" ::: "memory")

__device__ __forceinline__ u16 f2bf(float f) {
  unsigned int u = __float_as_uint(f);
  u += 0x7fffu + ((u >> 16) & 1u);
  return (u16)(u >> 16);
}
__device__ __forceinline__ float bf2f(u16 u) {
  return __uint_as_float(((unsigned)u) << 16);
}

// ---- fused prep: ln1 (4096) | wqkv^T (3072) | wout^T (1024) | rope+bnd (256) --
__global__ __launch_bounds__(256) void k_prep(const float* __restrict__ x, const float* __restrict__ ln1w,
                                              const float* __restrict__ ln1b, u16* __restrict__ hbuf,
                                              const float* __restrict__ wqkv, u16* __restrict__ wqkvT,
                                              const float* __restrict__ wout, u16* __restrict__ woutT,
                                              const int* __restrict__ seq, int* __restrict__ bnd,
                                              float* __restrict__ cosb, float* __restrict__ sinb) {
  __shared__ float tile[32][33];
  __shared__ float rb[2][4];
  const int bid = blockIdx.x, t = threadIdx.x;
  if (bid < 4096) {
    const int row = bid;
    const float4 xv = ((const float4*)(x + (size_t)row * DMODEL))[t];
    float s = xv.x + xv.y + xv.z + xv.w;
    float s2 = xv.x * xv.x + xv.y * xv.y + xv.z * xv.z + xv.w * xv.w;
#pragma unroll
    for (int m2 = 1; m2 < 64; m2 <<= 1) { s += __shfl_xor(s, m2); s2 += __shfl_xor(s2, m2); }
    int wv = t >> 6;
    if ((t & 63) == 0) { rb[0][wv] = s; rb[1][wv] = s2; }
    __syncthreads();
    s  = rb[0][0] + rb[0][1] + rb[0][2] + rb[0][3];
    s2 = rb[1][0] + rb[1][1] + rb[1][2] + rb[1][3];
    float mu = s * (1.0f / DMODEL);
    float rs = rsqrtf(s2 * (1.0f / DMODEL) - mu * mu + 1e-5f);
    const float4 wv4 = ((const float4*)ln1w)[t];
    const float4 bv4 = ((const float4*)ln1b)[t];
    ushort4 o;
    o.x = f2bf((xv.x - mu) * rs * wv4.x + bv4.x);
    o.y = f2bf((xv.y - mu) * rs * wv4.y + bv4.y);
    o.z = f2bf((xv.z - mu) * rs * wv4.z + bv4.z);
    o.w = f2bf((xv.w - mu) * rs * wv4.w + bv4.w);
    ((ushort4*)(hbuf + (size_t)row * DMODEL))[t] = o;
  } else if (bid < 4096 + 3072 + 1024) {
    const float* in; u16* out; int R, C, bx, by;
    if (bid < 4096 + 3072) { int rel = bid - 4096; in = wqkv; out = wqkvT; R = 1024; C = 3072; bx = rel % 96; by = rel / 96; }
    else                   { int rel = bid - 7168; in = wout; out = woutT; R = 1024; C = 1024; bx = rel % 32; by = rel / 32; }
    int c0 = bx * 32, r0 = by * 32;
    int tx = t & 31, ty = t >> 5;
#pragma unroll
    for (int i = 0; i < 32; i += 8)
      tile[ty + i][tx] = in[(size_t)(r0 + ty + i) * C + (c0 + tx)];
    __syncthreads();
#pragma unroll
    for (int i = 0; i < 32; i += 8)
      out[(size_t)(c0 + ty + i) * R + (r0 + tx)] = f2bf(tile[tx][ty + i]);
  } else {
    const int rel = bid - 8192;
    if (rel == 0 && t < BATCH * 5) {
      int b = t / 5, s = t % 5;
      const int* row = seq + b * LSEQ;
      int lo = 0, hi = LSEQ;
      while (lo < hi) { int mid = (lo + hi) >> 1; if (row[mid] < s) lo = mid + 1; else hi = mid; }
      bnd[b * 5 + s] = lo;
    }
    int idx = rel * 256 + t;
    if (idx < LSEQ * 32) {
      int l = idx >> 5, f = idx & 31;
      double inv = pow(10000.0, -(double)f / 32.0);
      float ang = (float)l * (float)inv;
      cosb[idx] = cosf(ang);
      sinb[idx] = sinf(ang);
    }
  }
}

// ============ 128x192 4-phase GEMM, C = A @ B^T (80 KB LDS -> 2 blocks/CU) =====
template<int OUTMODE>
__global__ __launch_bounds__(512, 4) void k_gemm256(const u16* __restrict__ A, const u16* __restrict__ B,
                                                    void* __restrict__ Cv, int M, int N, int K) {
  __shared__ __align__(16) u16 As[2][128 * 64];
  __shared__ __align__(16) u16 Bs[2][192 * 64];
  const int t = threadIdx.x, lane = t & 63, w = t >> 6;
  const int wr = w >> 2, wc = w & 3;
  const int nbx = N / 192;
  const int nwg = nbx * (M >> 7);
  const int cpx = nwg >> 3;
  const int bid = blockIdx.x;
  const int sw = (bid & 7) * cpx + (bid >> 3);
  const int m0 = (sw / nbx) * 128, n0 = (sw % nbx) * 192;
  const int NT = K >> 6;
  const int cg16 = (lane >> 4) * 16;

  f32x4 acc[4][3] = {};
  bf16x8 af_[2][2], bf_[3][2];
  const u16* Ap = A + (size_t)m0 * K;
  const u16* Bp = B + (size_t)n0 * K;
  const int rr0 = t >> 3;
  const int sz = ((t & 7) * 8) ^ ((rr0 & 7) << 3);
  const u16* pA[2] = { Ap + (size_t)rr0 * K + sz,
                       Ap + (size_t)(rr0 + 64) * K + sz };
  const u16* pB[3] = { Bp + (size_t)rr0 * K + sz,
                       Bp + (size_t)(rr0 + 64) * K + sz,
                       Bp + (size_t)(rr0 + 128) * K + sz };

#define SA1(b, h, EO) GLD((char*)As + (b)*16384 + (h)*8192 + w*1024, pA[h] + (EO))
#define SB3(b, EO) do { \
    GLD((char*)Bs + (b)*24576 +         w*1024, pB[0] + (EO)); \
    GLD((char*)Bs + (b)*24576 +  8192 + w*1024, pB[1] + (EO)); \
    GLD((char*)Bs + (b)*24576 + 16384 + w*1024, pB[2] + (EO)); \
  } while (0)

#define READ_AF(asb, mh) do { \
    _Pragma("unroll") for (int i2 = 0; i2 < 2; i2++) { \
      const int rowA = (((mh)*2 + i2)*2 + wr)*16 + (lane & 15); \
      const int sA = (rowA & 7) << 4; \
      _Pragma("unroll") for (int kk = 0; kk < 2; kk++) \
        af_[i2][kk] = *(const bf16x8*)((const char*)(asb) + (rowA & 63)*128 + ((kk*64 + cg16) ^ sA)); \
    } } while (0)
#define READ_BF(bsb) do { \
    _Pragma("unroll") for (int j2 = 0; j2 < 3; j2++) { \
      const int rowB = (j2*4 + wc)*16 + (lane & 15); \
      const int sB = (rowB & 7) << 4; \
      _Pragma("unroll") for (int kk = 0; kk < 2; kk++) \
        bf_[j2][kk] = *(const bf16x8*)((const char*)(bsb) + rowB*128 + ((kk*64 + cg16) ^ sB)); \
    } } while (0)
#define MFMA12(mh) do { \
    _Pragma("unroll") for (int kk = 0; kk < 2; kk++) \
      _Pragma("unroll") for (int i2 = 0; i2 < 2; i2++) \
        _Pragma("unroll") for (int j2 = 0; j2 < 3; j2++) \
          acc[(mh)*2+i2][j2] = __builtin_amdgcn_mfma_f32_16x16x32_bf16( \
              af_[i2][kk], bf_[j2][kk], acc[(mh)*2+i2][j2], 0, 0, 0); \
  } while (0)

  SA1(0, 0, 0); SA1(0, 1, 0); SB3(0, 0);
  SA1(1, 0, 64);
  VM(1);
  __builtin_amdgcn_s_barrier();

  const char* a0  = (const char*)As;
  const char* a0h = a0 + 8192;
  const char* a1  = a0 + 16384;
  const char* a1h = a0 + 24576;
  const char* b0  = (const char*)Bs;
  const char* b1  = b0 + 24576;
  const int NIT = NT >> 1;
  for (int i = 0; i < NIT; i++) {
    const bool lst = (i == NIT - 1);
    READ_AF(a0, 0); READ_BF(b0);
    SA1(1, 1, 64); SB3(1, 64);
    __builtin_amdgcn_s_barrier();
    asm volatile("s_waitcnt lgkmcnt(0)" ::: "memory");
    __builtin_amdgcn_s_setprio(1); MFMA12(0); __builtin_amdgcn_s_setprio(0);
    __builtin_amdgcn_s_barrier();
    READ_AF(a0h, 1);
    if (!lst) SA1(0, 0, 128);
    __builtin_amdgcn_s_barrier();
    asm volatile("s_waitcnt lgkmcnt(0)" ::: "memory");
    __builtin_amdgcn_s_setprio(1); MFMA12(1); __builtin_amdgcn_s_setprio(0);
    if (lst) VM(0); else VM(1);
    __builtin_amdgcn_s_barrier();
    READ_AF(a1, 0); READ_BF(b1);
    if (!lst) { SA1(0, 1, 128); SB3(0, 128); }
    __builtin_amdgcn_s_barrier();
    asm volatile("s_waitcnt lgkmcnt(0)" ::: "memory");
    __builtin_amdgcn_s_setprio(1); MFMA12(0); __builtin_amdgcn_s_setprio(0);
    __builtin_amdgcn_s_barrier();
    READ_AF(a1h, 1);
    if (!lst) SA1(1, 0, 192);
    __builtin_amdgcn_s_barrier();
    asm volatile("s_waitcnt lgkmcnt(0)" ::: "memory");
    __builtin_amdgcn_s_setprio(1); MFMA12(1); __builtin_amdgcn_s_setprio(0);
    if (!lst) VM(1);
    __builtin_amdgcn_s_barrier();
    pA[0] += 128; pA[1] += 128;
    pB[0] += 128; pB[1] += 128; pB[2] += 128;
  }
#undef MFMA12
#undef READ_BF
#undef READ_AF
#undef SA1
#undef SB3

  const int cr = (lane >> 4) * 4, cc = lane & 15;
#pragma unroll
  for (int fi = 0; fi < 4; fi++)
#pragma unroll
    for (int fj = 0; fj < 3; fj++) {
      const size_t roff = (size_t)(m0 + (fi * 2 + wr) * 16 + cr) * N + (n0 + (fj * 4 + wc) * 16 + cc);
      if (OUTMODE == 0) {
        float* Cp = (float*)Cv + roff;
#pragma unroll
        for (int r = 0; r < 4; r++) Cp[(size_t)r * N] = acc[fi][fj][r];
      } else {
        u16* Cp = (u16*)Cv + roff;
#pragma unroll
        for (int r = 0; r < 4; r++) Cp[(size_t)r * N] = f2bf(acc[fi][fj][r]);
      }
    }
}

// ---- bf16 GEMM 128x64 tile, chunked XCD swizzle, single-barrier loop (GEMM2) --
template<int OUTMODE>
__global__ __launch_bounds__(256) void k_gemm_bt(const u16* __restrict__ A, const u16* __restrict__ B,
                                                 void* __restrict__ Cv, int M, int N, int K) {
  __shared__ __align__(16) u16 As[2][128 * 64];
  __shared__ __align__(16) u16 Bs[2][64 * 64];
  const int t = threadIdx.x;
  const int lane = t & 63, w = t >> 6;
  const int nbx = N >> 6;
  const int nwg = nbx * (M >> 7);
  const int cpx = nwg >> 3;
  const int bid = blockIdx.x;
  const int sw = (bid & 7) * cpx + (bid >> 3);
  const int m0 = (sw / nbx) * 128, n0 = (sw % nbx) * 64;
  const int wm = (w >> 1) * 64, wn = (w & 1) * 32;
  const int NT = K >> 6;
  f32x4 acc[4][2] = {};
  const u16* Ap = A + (size_t)m0 * K;
  const u16* Bp = B + (size_t)n0 * K;
  const int cr0 = lane >> 3, cs = lane & 7;

#define GSTAGE(bb, kt_) do { \
    _Pragma("unroll") \
    for (int s2 = 0; s2 < 4; s2++) { \
      int ch = w * 4 + s2; \
      int row = ch * 8 + cr0; \
      int cb = cs ^ (row & 7); \
      GLD((char*)As[bb] + ch * 1024, Ap + (size_t)row * K + (kt_) * 64 + cb * 8); \
    } \
    _Pragma("unroll") \
    for (int s2 = 0; s2 < 2; s2++) { \
      int ch = w * 2 + s2; \
      int row = ch * 8 + cr0; \
      int cb = cs ^ (row & 7); \
      GLD((char*)Bs[bb] + ch * 1024, Bp + (size_t)row * K + (kt_) * 64 + cb * 8); \
    } } while (0)

  GSTAGE(0, 0);
  int cur = 0;
  for (int kt = 0; kt < NT; kt++) {
    VM(0);
    __builtin_amdgcn_s_barrier();
    __builtin_amdgcn_sched_barrier(0);
    if (kt + 1 < NT) GSTAGE(cur ^ 1, kt + 1);
    const u16* asb = As[cur];
    const u16* bsb = Bs[cur];
#pragma unroll
    for (int kk = 0; kk < 2; kk++) {
      bf16x8 af[4], bfr[2];
#pragma unroll
      for (int i = 0; i < 4; i++) {
        int rowa = wm + i * 16 + (lane & 15);
        af[i] = *(const bf16x8*)((const char*)asb + rowa * 128 + ((kk * 64 + (lane >> 4) * 16) ^ ((rowa & 7) << 4)));
      }
#pragma unroll
      for (int j = 0; j < 2; j++) {
        int rowb = wn + j * 16 + (lane & 15);
        bfr[j] = *(const bf16x8*)((const char*)bsb + rowb * 128 + ((kk * 64 + (lane >> 4) * 16) ^ ((rowb & 7) << 4)));
      }
      __builtin_amdgcn_s_setprio(1);
#pragma unroll
      for (int mf = 0; mf < 4; mf++)
#pragma unroll
        for (int nf = 0; nf < 2; nf++)
          acc[mf][nf] = __builtin_amdgcn_mfma_f32_16x16x32_bf16(af[mf], bfr[nf], acc[mf][nf], 0, 0, 0);
      __builtin_amdgcn_s_setprio(0);
    }
    __builtin_amdgcn_sched_barrier(0);
    cur ^= 1;
  }
#undef GSTAGE
  const int cr = (lane >> 4) * 4, cc = lane & 15;
#pragma unroll
  for (int mf = 0; mf < 4; mf++)
#pragma unroll
    for (int nf = 0; nf < 2; nf++) {
      if (OUTMODE == 0) {
        float* Cp = (float*)Cv + (size_t)(m0 + wm + mf * 16 + cr) * N + (n0 + wn + nf * 16 + cc);
#pragma unroll
        for (int r = 0; r < 4; r++) Cp[(size_t)r * N] = acc[mf][nf][r];
      } else {
        u16* Cp = (u16*)Cv + (size_t)(m0 + wm + mf * 16 + cr) * N + (n0 + wn + nf * 16 + cc);
#pragma unroll
        for (int r = 0; r < 4; r++) Cp[(size_t)r * N] = f2bf(acc[mf][nf][r]);
      }
    }
}

// ---- fused: q/k LN+RoPE+split (4096 blocks, shfl-based) | V^T (4096 blocks) ---
__global__ __launch_bounds__(256) void k_qkv_post(const u16* __restrict__ qkv,
                                                  const float* __restrict__ qw, const float* __restrict__ kw,
                                                  const float* __restrict__ cosb, const float* __restrict__ sinb,
                                                  u16* __restrict__ Q, u16* __restrict__ K, u16* __restrict__ VT) {
  const int bid = blockIdx.x, t = threadIdx.x;
  if (bid < 4096) {
    __shared__ float rb[4][4];
    int row = bid;
    int b = row >> 11, l = row & 2047;
    const u16* base = qkv + (size_t)row * 3072;
    ushort4 qu = ((const ushort4*)base)[t];
    ushort4 ku = ((const ushort4*)(base + 1024))[t];
    float qx = bf2f(qu.x), qy = bf2f(qu.y), qz = bf2f(qu.z), qw_ = bf2f(qu.w);
    float kx = bf2f(ku.x), ky = bf2f(ku.y), kz = bf2f(ku.z), kw_ = bf2f(ku.w);
    float red[4];
    red[0] = qx + qy + qz + qw_;
    red[1] = qx * qx + qy * qy + qz * qz + qw_ * qw_;
    red[2] = kx + ky + kz + kw_;
    red[3] = kx * kx + ky * ky + kz * kz + kw_ * kw_;
#pragma unroll
    for (int i = 0; i < 4; i++)
#pragma unroll
      for (int m2 = 1; m2 < 64; m2 <<= 1) red[i] += __shfl_xor(red[i], m2);
    int w = t >> 6;
    if ((t & 63) == 0) { rb[w][0] = red[0]; rb[w][1] = red[1]; rb[w][2] = red[2]; rb[w][3] = red[3]; }
    __syncthreads();
    float S1 = rb[0][0] + rb[1][0] + rb[2][0] + rb[3][0];
    float S2 = rb[0][1] + rb[1][1] + rb[2][1] + rb[3][1];
    float S3 = rb[0][2] + rb[1][2] + rb[2][2] + rb[3][2];
    float S4 = rb[0][3] + rb[1][3] + rb[2][3] + rb[3][3];
    float muq = S1 * (1.0f / DMODEL), rsq = rsqrtf(S2 * (1.0f / DMODEL) - muq * muq + 1e-5f);
    float muk = S3 * (1.0f / DMODEL), rsk = rsqrtf(S4 * (1.0f / DMODEL) - muk * muk + 1e-5f);
    float4 qwv = ((const float4*)qw)[t];
    float4 kwv = ((const float4*)kw)[t];
    float qn[4], kn[4];
    qn[0] = (qx - muq) * rsq * qwv.x;  kn[0] = (kx - muk) * rsk * kwv.x;
    qn[1] = (qy - muq) * rsq * qwv.y;  kn[1] = (ky - muk) * rsk * kwv.y;
    qn[2] = (qz - muq) * rsq * qwv.z;  kn[2] = (kz - muk) * rsk * kwv.z;
    qn[3] = (qw_ - muq) * rsq * qwv.w; kn[3] = (kw_ - muk) * rsk * kwv.w;
    const float sgn = (t & 8) ? 1.0f : -1.0f;
    int d0 = t * 4;
    int hh = d0 >> 6;
    union { ushort4 v4; u16 e[4]; } qo, ko;
#pragma unroll
    for (int i = 0; i < 4; i++) {
      int fr = (t & 7) * 4 + i;
      float c = cosb[l * 32 + fr], s = sinb[l * 32 + fr];
      float q2 = sgn * __shfl_xor(qn[i], 8);
      float k2 = sgn * __shfl_xor(kn[i], 8);
      qo.e[i] = f2bf(qn[i] * c + q2 * s);
      ko.e[i] = f2bf(kn[i] * c + k2 * s);
    }
    size_t oidx = ((size_t)(b * NHEAD + hh) * LSEQ + l) * DHEAD + (d0 & 63);
    *(ushort4*)(Q + oidx) = qo.v4;
    *(ushort4*)(K + oidx) = ko.v4;
  } else {
    __shared__ u16 vtile[32][33];
    const int rel = bid - 4096;
    const int hd = rel >> 7;
    const int tl = rel & 127;
    const int d0 = (tl & 1) * 32, l0 = (tl >> 1) * 32;
    const int gl = (hd >> 4) * LSEQ;
    const u16* ip = qkv + (size_t)(gl + l0) * 3072 + 2048 + (hd & 15) * 64 + d0;
    u16* op = VT + (size_t)hd * LSEQ * DHEAD + (size_t)d0 * LSEQ + l0;
    int tx = t & 31, ty = t >> 5;
#pragma unroll
    for (int i = 0; i < 32; i += 8)
      vtile[ty + i][tx] = ip[(size_t)(ty + i) * 3072 + tx];
    __syncthreads();
#pragma unroll
    for (int i = 0; i < 32; i += 8)
      op[(size_t)(ty + i) * LSEQ + tx] = vtile[tx][ty + i];
  }
}

// -- segment-masked flash attention: QBLK=128, 8 waves, single-barrier 2-deep ---
__global__ __launch_bounds__(512) void k_attn(const u16* __restrict__ Q, const u16* __restrict__ Kb,
                                              const u16* __restrict__ VTb, const int* __restrict__ seq,
                                              const int* __restrict__ bnd, u16* __restrict__ ctx) {
  __shared__ __align__(16) u16 Ks[2][64 * 64];
  __shared__ __align__(16) u16 Vs[2][64 * 64];
  __shared__ __align__(16) u16 Pw[8][16 * 64];

  const int bid = blockIdx.x;
  const int sw = (bid & 7) * 64 + (bid >> 3);
  const int qt = sw & 15, h = (sw >> 4) & 15, b = sw >> 8;
  const int t = threadIdx.x, l = t & 63, w = t >> 6;
  const int c = l & 15, g = l >> 4;
  const int q0 = qt * 128;
  const size_t hoff = (size_t)(b * NHEAD + h) * LSEQ * DHEAD;
  const u16* Qg = Q + hoff;
  const u16* Kg = Kb + hoff;
  const u16* Vg = VTb + hoff;   // [d][l]
  const int* seqb = seq + b * LSEQ;
  const int* bnd5 = bnd + b * 5;

  const int qw0 = q0 + w * 16;
  const int myq = qw0 + c;
  const int sq = seqb[myq];
  const int lo = bnd5[sq], hi = bnd5[sq + 1];
  const int wlo = bnd5[seqb[qw0]];
  const int whi = bnd5[seqb[qw0 + 15] + 1];
  int kbeg = bnd5[seqb[q0]] & ~63;
  int kend = (bnd5[seqb[q0 + 127] + 1] + 63) & ~63;
  if (kend > LSEQ) kend = LSEQ;

  bf16x8 qf[2];
  qf[0] = *(const bf16x8*)(Qg + (size_t)myq * 64 + g * 8);
  qf[1] = *(const bf16x8*)(Qg + (size_t)myq * 64 + 32 + g * 8);

  f32x4 acc[4] = {};
  float lsum = 0.f;

  const int rr = t >> 3;
  const int szk = ((t & 7) * 8) ^ ((rr & 7) << 3);
  const u16* pK = Kg + (size_t)rr * 64 + szk;
  const u16* pV = Vg + (size_t)rr * LSEQ + szk;

#define STAGE(bb, kt_) do { \
    GLD((char*)Ks[bb] + w * 1024, pK + (size_t)(kt_) * 64); \
    GLD((char*)Vs[bb] + w * 1024, pV + (kt_)); \
  } while (0)

  STAGE(0, kbeg);
  int cur = 0;
  for (int kt = kbeg; kt < kend; kt += 64) {
    VM(0);
    __builtin_amdgcn_s_barrier();
    __builtin_amdgcn_sched_barrier(0);
    if (kt + 64 < kend) STAGE(cur ^ 1, kt + 64);
    if (kt < whi && kt + 64 > wlo) {
      const u16* ksb = Ks[cur];
      const u16* vsb = Vs[cur];
      f32x4 st[4] = {};
#pragma unroll
      for (int kk = 0; kk < 2; kk++) {
        bf16x8 kf[4];
#pragma unroll
        for (int i = 0; i < 4; i++) {
          int row = i * 16 + c;
          kf[i] = *(const bf16x8*)((const char*)ksb + row * 128 + ((kk * 64 + g * 16) ^ ((row & 7) << 4)));
        }
        __builtin_amdgcn_s_setprio(1);
#pragma unroll
        for (int i = 0; i < 4; i++)
          st[i] = __builtin_amdgcn_mfma_f32_16x16x32_bf16(kf[i], qf[kk], st[i], 0, 0, 0);
        __builtin_amdgcn_s_setprio(0);
      }
      const int kb0 = kt + g * 4;
#pragma unroll
      for (int i = 0; i < 4; i++) {
        float p[4];
#pragma unroll
        for (int r = 0; r < 4; r++) {
          int kglob = kb0 + i * 16 + r;
          bool ok = ((unsigned)(kglob - lo)) < ((unsigned)(hi - lo));
          float x = ok ? fmaf(st[i][r], 0.125f, -8.0f) : -1e30f;
          p[r] = __expf(x);
          lsum += p[r];
        }
        unsigned w0, w1;
        asm("v_cvt_pk_bf16_f32 %0, %1, %2" : "=v"(w0) : "v"(p[0]), "v"(p[1]));
        asm("v_cvt_pk_bf16_f32 %0, %1, %2" : "=v"(w1) : "v"(p[2]), "v"(p[3]));
        uint2 wp; wp.x = w0; wp.y = w1;
        *(uint2*)((char*)Pw[w] + c * 128 + ((i * 32 + g * 8) ^ ((c & 7) << 4))) = wp;
      }
#pragma unroll
      for (int kk = 0; kk < 2; kk++) {
        bf16x8 pa = *(const bf16x8*)((char*)Pw[w] + c * 128 + ((kk * 64 + g * 16) ^ ((c & 7) << 4)));
        bf16x8 vf[4];
#pragma unroll
        for (int df = 0; df < 4; df++) {
          int row = df * 16 + c;
          vf[df] = *(const bf16x8*)((const char*)vsb + row * 128 + ((kk * 64 + g * 16) ^ ((row & 7) << 4)));
        }
        __builtin_amdgcn_s_setprio(1);
#pragma unroll
        for (int df = 0; df < 4; df++)
          acc[df] = __builtin_amdgcn_mfma_f32_16x16x32_bf16(pa, vf[df], acc[df], 0, 0, 0);
        __builtin_amdgcn_s_setprio(0);
      }
    }
    __builtin_amdgcn_sched_barrier(0);
    cur ^= 1;
  }
#undef STAGE

  lsum += __shfl_xor(lsum, 16);
  lsum += __shfl_xor(lsum, 32);
#pragma unroll
  for (int r = 0; r < 4; r++) {
    float lr = __shfl(lsum, g * 4 + r, 64);
    float rls = 1.0f / lr;
    int qrow = qw0 + g * 4 + r;
    u16* op = ctx + (size_t)(b * LSEQ + qrow) * DMODEL + h * 64 + c;
#pragma unroll
    for (int df = 0; df < 4; df++)
      op[df * 16] = f2bf(acc[df][r] * rls);
  }
}

// ---------------- launch --------------------------------------------------------
extern "C" void kernel_launch(void* const* d_in, const int* in_sizes, int n_in,
                              void* d_out, int out_size, void* d_ws, size_t ws_size,
                              hipStream_t stream) {
  const float* x    = (const float*)d_in[0];
  const int*   seq  = (const int*)d_in[1];
  const float* ln1w = (const float*)d_in[2];
  const float* ln1b = (const float*)d_in[3];
  const float* wqkv = (const float*)d_in[4];
  const float* qlnw = (const float*)d_in[5];
  const float* klnw = (const float*)d_in[6];
  const float* wout = (const float*)d_in[7];
  float* out = (float*)d_out;

  char* p = (char*)d_ws;
  u16* wqkvT = (u16*)p;  p += (size_t)3072 * 1024 * 2;
  u16* woutT = (u16*)p;  p += (size_t)1024 * 1024 * 2;
  u16* hbuf  = (u16*)p;  p += (size_t)ROWS * DMODEL * 2;
  u16* Qb    = (u16*)p;  p += (size_t)ROWS * DMODEL * 2;
  u16* Kbuf  = (u16*)p;  p += (size_t)ROWS * DMODEL * 2;
  u16* VTbuf = (u16*)p;  p += (size_t)ROWS * DMODEL * 2;
  u16* ctxb  = (u16*)p;  p += (size_t)ROWS * DMODEL * 2;
  float* cosb = (float*)p; p += (size_t)LSEQ * 32 * 4;
  float* sinb = (float*)p; p += (size_t)LSEQ * 32 * 4;
  int* bnd   = (int*)p;  p += 256;
  u16* qkv   = (u16*)p;  p += (size_t)ROWS * 3072 * 2;

  k_prep<<<8448, 256, 0, stream>>>(x, ln1w, ln1b, hbuf, wqkv, wqkvT, wout, woutT, seq, bnd, cosb, sinb);
  k_gemm256<1><<<(ROWS / 128) * (3072 / 192), 512, 0, stream>>>(hbuf, wqkvT, (void*)qkv, ROWS, 3072, 1024);
  k_qkv_post<<<8192, 256, 0, stream>>>(qkv, qlnw, klnw, cosb, sinb, Qb, Kbuf, VTbuf);
  k_attn<<<BATCH * NHEAD * (LSEQ / 128), 512, 0, stream>>>(Qb, Kbuf, VTbuf, seq, bnd, ctxb);
  k_gemm_bt<0><<<(ROWS / 128) * (1024 / 64), 256, 0, stream>>>(ctxb, woutT, (void*)out, ROWS, 1024, 1024);
}